// Round 1
// baseline (14086.996 us; speedup 1.0000x reference)
//
#include <hip/hip_runtime.h>
#include <hip/hip_fp16.h>
#include <stdint.h>

#define TSTEPS 512
#define BATCH  512
#define FEAT   128
#define HID    512
#define NGATE  2048   // 4*HID

typedef _Float16 half8 __attribute__((ext_vector_type(8)));
typedef _Float16 half4v __attribute__((ext_vector_type(4)));
typedef float    floatx4 __attribute__((ext_vector_type(4)));

// ---------------- ws layout (bytes) ----------------
#define OFF_WIH1 0u
#define SZ_WIH1  ((unsigned)(NGATE*FEAT*2))          // 512 KB
#define OFF_WHH1 (OFF_WIH1+SZ_WIH1)
#define SZ_WHH   ((unsigned)(NGATE*HID*2))           // 2 MB
#define OFF_WIH2 (OFF_WHH1+SZ_WHH)
#define OFF_WHH2 (OFF_WIH2+SZ_WHH)
#define OFF_B1   (OFF_WHH2+SZ_WHH)
#define OFF_B2   (OFF_B1+(unsigned)(NGATE*4))
#define OFF_H1   (OFF_B2+(unsigned)(NGATE*4))        // 2 parity buffers, f16
#define SZ_H     ((unsigned)(2*BATCH*HID*2))
#define OFF_H2   (OFF_H1+SZ_H)
#define OFF_C1   (OFF_H2+SZ_H)
#define SZ_C     ((unsigned)(BATCH*HID*4))
#define OFF_C2   (OFF_C1+SZ_C)
#define WS_END   (OFF_C2+SZ_C)

#define GLOBAL_AS __attribute__((address_space(1)))
#define LDS_AS    __attribute__((address_space(3)))

__device__ __forceinline__ void gload_lds16(const void* g, void* l) {
  __builtin_amdgcn_global_load_lds((const GLOBAL_AS void*)g, (LDS_AS void*)l, 16, 0, 0);
}

__device__ __forceinline__ half8 ldfrag(const _Float16* S, int r, int ko) {
  const int s = ko ^ (r & 3) ^ ((r >> 2) & 3);
  return *(const half8*)(S + r * 32 + s * 8);
}

// -------- prep kernels --------
__global__ void k_conv4(const float* __restrict__ s, _Float16* __restrict__ d, int n4) {
  int i = blockIdx.x * blockDim.x + threadIdx.x;
  if (i < n4) {
    const float4 v = ((const float4*)s)[i];
    half4v h; h[0] = (_Float16)v.x; h[1] = (_Float16)v.y; h[2] = (_Float16)v.z; h[3] = (_Float16)v.w;
    ((half4v*)d)[i] = h;
  }
}

__global__ void k_bias(const float* __restrict__ a, const float* __restrict__ b,
                       float* __restrict__ d, int n) {
  int i = blockIdx.x * blockDim.x + threadIdx.x;
  if (i < n) d[i] = a[i] + b[i];
}

// -------- per-step LSTM cell kernel --------
// gates[b][j] = sum_k x[b,k]*Wx[j,k]  +  sum_k hin[b,k]*Wh[j,k]  + bias[j]
// Block: 256 thr (4 waves, 2x2 wave grid), out tile 64 batch x 64 gate cols.
// Gate cols of a block = 4 types x 16 hcols (type stride 512), so i/f/g/o for a
// given (b,hcol) are block-local -> LSTM update fused in epilogue.
template<bool XF32, int KX, bool DO_OUT>
__global__ __launch_bounds__(256)
void k_cell(const void* __restrict__ xsrc,          // [BATCH][KX] f32 (XF32) or f16
            const _Float16* __restrict__ Wx,        // [NGATE][KX] f16
            const _Float16* __restrict__ Wh,        // [NGATE][HID] f16
            const float* __restrict__ bias,         // [NGATE]
            const _Float16* __restrict__ hin,       // [BATCH][HID] f16
            _Float16* __restrict__ hout,            // [BATCH][HID] f16
            float* __restrict__ cst,                // [BATCH][HID] f32
            const float* __restrict__ Wlin,         // [2][HID] (DO_OUT)
            const float* __restrict__ blin,         // [2]
            float* __restrict__ out,                // [BATCH][TSTEPS*2]
            int tstep)
{
  __shared__ __align__(16) _Float16 As[64 * 32];
  __shared__ __align__(16) _Float16 Bs[64 * 32];
  __shared__ float gs[64][65];
  __shared__ float hs[64][17];

  const int tid  = threadIdx.x;
  const int lane = tid & 63;
  const int wave = tid >> 6;
  const int wm = wave >> 1, wn = wave & 1;
  const int bx = blockIdx.x;   // batch group 0..7
  const int hg = blockIdx.y;   // hcol group 0..31

  // staging mapping: thread i covers LDS bytes [i*16, i*16+16) = row i/4, slot i%4
  const int r_st  = tid >> 2;
  const int s_st  = tid & 3;
  const int ko_st = s_st ^ (r_st & 3) ^ ((r_st >> 2) & 3);  // k-chunk held by this slot
  const int arow  = bx * 64 + r_st;
  const int brow  = ((r_st >> 4) * HID) + hg * 16 + (r_st & 15);  // W row for lds row r_st

  _Float16* AsW = As + wave * 512;   // wave-uniform LDS dest (lane*16B auto-offset)
  _Float16* BsW = Bs + wave * 512;

  floatx4 acc[2][2];
  #pragma unroll
  for (int a = 0; a < 2; a++)
    #pragma unroll
    for (int b = 0; b < 2; b++) acc[a][b] = (floatx4){0.f, 0.f, 0.f, 0.f};

  const int fr_a = wm * 32 + (lane & 15);
  const int fr_b = wn * 32 + (lane & 15);
  const int fko  = lane >> 4;

  // ---- phase X: K = KX over xsrc/Wx ----
  for (int kt = 0; kt < KX; kt += 32) {
    __syncthreads();
    if constexpr (XF32) {
      const float* xf = (const float*)xsrc + (size_t)arow * KX + kt + ko_st * 8;
      float4 v0 = *(const float4*)xf;
      float4 v1 = *(const float4*)(xf + 4);
      half8 h;
      h[0] = (_Float16)v0.x; h[1] = (_Float16)v0.y; h[2] = (_Float16)v0.z; h[3] = (_Float16)v0.w;
      h[4] = (_Float16)v1.x; h[5] = (_Float16)v1.y; h[6] = (_Float16)v1.z; h[7] = (_Float16)v1.w;
      *(half8*)(As + tid * 8) = h;
    } else {
      const _Float16* xh = (const _Float16*)xsrc + (size_t)arow * KX + kt + ko_st * 8;
      gload_lds16(xh, AsW);
    }
    gload_lds16(Wx + (size_t)brow * KX + kt + ko_st * 8, BsW);
    __syncthreads();
    half8 a0 = ldfrag(As, fr_a, fko);
    half8 a1 = ldfrag(As, fr_a + 16, fko);
    half8 b0 = ldfrag(Bs, fr_b, fko);
    half8 b1 = ldfrag(Bs, fr_b + 16, fko);
    acc[0][0] = __builtin_amdgcn_mfma_f32_16x16x32_f16(a0, b0, acc[0][0], 0, 0, 0);
    acc[0][1] = __builtin_amdgcn_mfma_f32_16x16x32_f16(a0, b1, acc[0][1], 0, 0, 0);
    acc[1][0] = __builtin_amdgcn_mfma_f32_16x16x32_f16(a1, b0, acc[1][0], 0, 0, 0);
    acc[1][1] = __builtin_amdgcn_mfma_f32_16x16x32_f16(a1, b1, acc[1][1], 0, 0, 0);
  }

  // ---- phase H: K = HID over hin/Wh ----
  for (int kt = 0; kt < HID; kt += 32) {
    __syncthreads();
    gload_lds16(hin + (size_t)arow * HID + kt + ko_st * 8, AsW);
    gload_lds16(Wh + (size_t)brow * HID + kt + ko_st * 8, BsW);
    __syncthreads();
    half8 a0 = ldfrag(As, fr_a, fko);
    half8 a1 = ldfrag(As, fr_a + 16, fko);
    half8 b0 = ldfrag(Bs, fr_b, fko);
    half8 b1 = ldfrag(Bs, fr_b + 16, fko);
    acc[0][0] = __builtin_amdgcn_mfma_f32_16x16x32_f16(a0, b0, acc[0][0], 0, 0, 0);
    acc[0][1] = __builtin_amdgcn_mfma_f32_16x16x32_f16(a0, b1, acc[0][1], 0, 0, 0);
    acc[1][0] = __builtin_amdgcn_mfma_f32_16x16x32_f16(a1, b0, acc[1][0], 0, 0, 0);
    acc[1][1] = __builtin_amdgcn_mfma_f32_16x16x32_f16(a1, b1, acc[1][1], 0, 0, 0);
  }

  // ---- epilogue: gates tile -> LDS ----
  #pragma unroll
  for (int mi = 0; mi < 2; mi++)
    #pragma unroll
    for (int ni = 0; ni < 2; ni++) {
      const int row = wm * 32 + mi * 16 + (lane >> 4) * 4;
      const int col = wn * 32 + ni * 16 + (lane & 15);
      #pragma unroll
      for (int r = 0; r < 4; r++) gs[row + r][col] = acc[mi][ni][r];
    }
  __syncthreads();

  // ---- LSTM elementwise update (block-local: cols = i,f,g,o x 16 hcols) ----
  for (int it = tid; it < 64 * 16; it += 256) {
    const int b = it >> 4, lc = it & 15;
    const int hcol = hg * 16 + lc;
    const float iv = gs[b][lc]      + bias[hcol];
    const float fv = gs[b][16 + lc] + bias[HID + hcol];
    const float gv = gs[b][32 + lc] + bias[2 * HID + hcol];
    const float ov = gs[b][48 + lc] + bias[3 * HID + hcol];
    const float ig = 1.f / (1.f + __expf(-iv));
    const float fg = 1.f / (1.f + __expf(-fv));
    const float og = 1.f / (1.f + __expf(-ov));
    const float tg = 1.f - 2.f / (__expf(2.f * gv) + 1.f);
    const int gidx = (bx * 64 + b) * HID + hcol;
    const float cn = fg * cst[gidx] + ig * tg;
    const float tc = 1.f - 2.f / (__expf(2.f * cn) + 1.f);
    const float hn = og * tc;
    cst[gidx] = cn;
    hout[gidx] = (_Float16)hn;
    if (DO_OUT) hs[b][lc] = hn;
  }

  if (DO_OUT) {
    __syncthreads();
    if (tid < 128) {
      const int b = tid >> 1, tag = tid & 1;
      float sv = 0.f;
      #pragma unroll
      for (int lc = 0; lc < 16; lc++)
        sv += hs[b][lc] * Wlin[tag * HID + hg * 16 + lc];
      if (hg == 0) sv += blin[tag];
      atomicAdd(&out[(size_t)(bx * 64 + b) * (TSTEPS * 2) + tstep * 2 + tag], sv);
    }
  }
}

// ---------------- host ----------------
extern "C" void kernel_launch(void* const* d_in, const int* in_sizes, int n_in,
                              void* d_out, int out_size, void* d_ws, size_t ws_size,
                              hipStream_t stream)
{
  const float* signal = (const float*)d_in[0];
  const float* Wih1 = (const float*)d_in[1];
  const float* Whh1 = (const float*)d_in[2];
  const float* bih1 = (const float*)d_in[3];
  const float* bhh1 = (const float*)d_in[4];
  const float* Wih2 = (const float*)d_in[5];
  const float* Whh2 = (const float*)d_in[6];
  const float* bih2 = (const float*)d_in[7];
  const float* bhh2 = (const float*)d_in[8];
  const float* Wlin = (const float*)d_in[9];
  const float* blin = (const float*)d_in[10];

  char* ws = (char*)d_ws;
  _Float16* wih1h = (_Float16*)(ws + OFF_WIH1);
  _Float16* whh1h = (_Float16*)(ws + OFF_WHH1);
  _Float16* wih2h = (_Float16*)(ws + OFF_WIH2);
  _Float16* whh2h = (_Float16*)(ws + OFF_WHH2);
  float* b1 = (float*)(ws + OFF_B1);
  float* b2 = (float*)(ws + OFF_B2);
  _Float16* h1 = (_Float16*)(ws + OFF_H1);   // [2][BATCH*HID]
  _Float16* h2 = (_Float16*)(ws + OFF_H2);
  float* c1 = (float*)(ws + OFF_C1);
  float* c2 = (float*)(ws + OFF_C2);
  float* out = (float*)d_out;

  // zero state (h1,h2,c1,c2 are contiguous) and output (bias added by hg==0 blocks)
  hipMemsetAsync(ws + OFF_H1, 0, (size_t)(SZ_H * 2 + SZ_C * 2), stream);
  hipMemsetAsync(d_out, 0, (size_t)out_size * 4, stream);

  const int thr = 256;
  k_conv4<<<(NGATE * FEAT / 4 + thr - 1) / thr, thr, 0, stream>>>(Wih1, wih1h, NGATE * FEAT / 4);
  k_conv4<<<(NGATE * HID  / 4 + thr - 1) / thr, thr, 0, stream>>>(Whh1, whh1h, NGATE * HID / 4);
  k_conv4<<<(NGATE * HID  / 4 + thr - 1) / thr, thr, 0, stream>>>(Wih2, wih2h, NGATE * HID / 4);
  k_conv4<<<(NGATE * HID  / 4 + thr - 1) / thr, thr, 0, stream>>>(Whh2, whh2h, NGATE * HID / 4);
  k_bias<<<(NGATE + thr - 1) / thr, thr, 0, stream>>>(bih1, bhh1, b1, NGATE);
  k_bias<<<(NGATE + thr - 1) / thr, thr, 0, stream>>>(bih2, bhh2, b2, NGATE);

  dim3 grid(8, 32), block(256);
  for (int t = 0; t < TSTEPS; t++) {
    const int pin = t & 1, pout = (t + 1) & 1;
    k_cell<true, FEAT, false><<<grid, block, 0, stream>>>(
        (const void*)(signal + (size_t)t * BATCH * FEAT), wih1h, whh1h, b1,
        h1 + (size_t)pin * BATCH * HID, h1 + (size_t)pout * BATCH * HID, c1,
        nullptr, nullptr, nullptr, t);
    k_cell<false, HID, true><<<grid, block, 0, stream>>>(
        (const void*)(h1 + (size_t)pout * BATCH * HID), wih2h, whh2h, b2,
        h2 + (size_t)pin * BATCH * HID, h2 + (size_t)pout * BATCH * HID, c2,
        Wlin, blin, out, t);
  }
}